// Round 2
// baseline (620.536 us; speedup 1.0000x reference)
//
#include <hip/hip_runtime.h>
#include <hip/hip_bf16.h>
#include <stdint.h>

// HierarchicalGRU on MI355X. B=16384, IN=4096, H=128, NOPT=64.
// Round 6: attack the 11.5% occupancy (1 wave/SIMD grid). Same fused
// attn->gru0->gru1 dataflow, but each 16-row tile is now worked by FOUR waves
// (N-split: 2 of 8 col-blocks per wave in the GEMMs, 1 of 4 in the heads).
// 1024 blocks x 256 thr = 4096 waves = 4/SIMD. Full-K per wave, so no
// partial-sum reduction; shared 4KB sX/sC tiles + 4 phase barriers.

typedef __attribute__((ext_vector_type(8))) short bf16x8;
typedef __attribute__((ext_vector_type(4))) float f32x4;
typedef __attribute__((ext_vector_type(8))) float f32x8;

#define INDIM 4096
#define H 128
#define NOPT 64

// workspace layout (uint16 element offsets), bf16 contents
#define WS_WAT    0u        // [128, 4096]
#define WS_WIH0T  524288u   // [384, 128]
#define WS_WHH0T  573440u   // [384, 128]
#define WS_WIH1T  622592u   // [384, 256]
#define WS_WHH1T  720896u   // [384, 128]
#define WS_WV0T   770048u   // [64, 128]
#define WS_WV1T   778240u   // [64, 128]
#define WS_WT0T   786432u   // [64, 128]

// output layout (fp32 element offsets): v0[B,64], term_p[B,1], v1[B,64], h0n[B,128], h1n[B,128]
#define OUT_V0    0u
#define OUT_TERMP 1048576u
#define OUT_V1    1064960u
#define OUT_H0N   2113536u
#define OUT_H1N   4210688u

static __device__ __forceinline__ uint16_t f2bf(float f) {
  __hip_bfloat16 h = __float2bfloat16(f);   // RNE; compiler packs pairs into v_cvt_pk_bf16_f32
  return __builtin_bit_cast(uint16_t, h);
}
static __device__ __forceinline__ float sigm(float x) { return 1.0f / (1.0f + __expf(-x)); }
static __device__ __forceinline__ float fast_tanh(float x) {
  float e = __expf(2.0f * x);          // e=inf -> 1, e=0 -> -1: saturates correctly
  return 1.0f - 2.0f / (e + 1.0f);
}
static __device__ __forceinline__ f32x4 mfma16(bf16x8 a, bf16x8 b, f32x4 c) {
  return __builtin_amdgcn_mfma_f32_16x16x32_bf16(a, b, c, 0, 0, 0);
}
static __device__ __forceinline__ bf16x8 cvt8(f32x8 v) {
  bf16x8 r;
#pragma unroll
  for (int j = 0; j < 8; ++j) r[j] = (short)f2bf(v[j]);
  return r;
}

// ---------------- K0: weight transpose+convert  W[K,N] fp32 -> WT[N,K] bf16 ----------------
__global__ void k_transpose(const float* __restrict__ Wa,
                            const float* __restrict__ Wih0,
                            const float* __restrict__ Whh0,
                            const float* __restrict__ Wih1,
                            const float* __restrict__ Whh1,
                            const float* __restrict__ Wv0,
                            const float* __restrict__ Wv1,
                            const float* __restrict__ Wt0,
                            uint16_t* __restrict__ ws) {
  int blk = blockIdx.x;
  const float* in; uint16_t* out; int ksh; int N; int base;
  if (blk < 2048)      { in = Wa;   out = ws + WS_WAT;   ksh = 12; N = 128; base = 0; }
  else if (blk < 2240) { in = Wih0; out = ws + WS_WIH0T; ksh = 7;  N = 384; base = 2048; }
  else if (blk < 2432) { in = Whh0; out = ws + WS_WHH0T; ksh = 7;  N = 384; base = 2240; }
  else if (blk < 2816) { in = Wih1; out = ws + WS_WIH1T; ksh = 8;  N = 384; base = 2432; }
  else if (blk < 3008) { in = Whh1; out = ws + WS_WHH1T; ksh = 7;  N = 384; base = 2816; }
  else if (blk < 3040) { in = Wv0;  out = ws + WS_WV0T;  ksh = 7;  N = 64;  base = 3008; }
  else if (blk < 3072) { in = Wv1;  out = ws + WS_WV1T;  ksh = 7;  N = 64;  base = 3040; }
  else                 { in = Wt0;  out = ws + WS_WT0T;  ksh = 7;  N = 64;  base = 3072; }
  int e = (blk - base) * 256 + (int)threadIdx.x;
  int n = e >> ksh;
  int k = e & ((1 << ksh) - 1);
  out[e] = f2bf(in[(size_t)k * N + n]);
}

// ---------------- K1: fused attn -> gru0(+v0/term) -> gru1(+v1) ----------------
// 1024 blocks x 256 thr (4 waves). Block owns 16 rows; wave w owns N-blocks
// {2w, 2w+1} of the 128-wide GEMMs and col-block w of the 64-wide heads.
__launch_bounds__(256, 4)
__global__ void k_fused(const float* __restrict__ obs,
                        const uint16_t* __restrict__ ws,
                        const float* __restrict__ ba,
                        const float* __restrict__ h0,
                        const float* __restrict__ bih0,
                        const float* __restrict__ bhh0,
                        const float* __restrict__ bv0,
                        const float* __restrict__ bt0,
                        const int* __restrict__ chosen,
                        const float* __restrict__ h1,
                        const float* __restrict__ bih1,
                        const float* __restrict__ bhh1,
                        const float* __restrict__ bv1,
                        float* __restrict__ out) {
  // 16 rows x 16 k-slots x 8 elts, XOR-swizzled (kb ^ row). Shared by all 4 waves.
  __shared__ uint16_t sX[16 * 16 * 8];   // attn tile (A-frag layout)
  __shared__ uint16_t sC[16 * 16 * 8];   // hc tile (reused for hc0 then hc1)
  const uint16_t* WaT   = ws + WS_WAT;
  const uint16_t* Wih0T = ws + WS_WIH0T;
  const uint16_t* Whh0T = ws + WS_WHH0T;
  const uint16_t* Wih1T = ws + WS_WIH1T;
  const uint16_t* Whh1T = ws + WS_WHH1T;
  const uint16_t* Wv0T  = ws + WS_WV0T;
  const uint16_t* Wv1T  = ws + WS_WV1T;
  const uint16_t* Wt0T  = ws + WS_WT0T;
  const int t = threadIdx.x, w = t >> 6, lane = t & 63;
  const int l15 = lane & 15, quad = lane >> 4;
  const int row0 = blockIdx.x * 16;        // block's 16 rows
  const int nbA = 2 * w;                   // wave's first N-block (of 8)

  // ---- Phase A: attn = tanh(obs @ WaT^T + ba), wave computes cols [32w, 32w+32) ----
  f32x4 acc0 = {}, acc1 = {};
  {
    const float*    arow  = obs + (size_t)(row0 + l15) * INDIM + quad * 8;
    const uint16_t* brow0 = WaT + (size_t)(nbA * 16 + l15) * INDIM + quad * 8;
    const uint16_t* brow1 = brow0 + (size_t)16 * INDIM;
#pragma unroll 2
    for (int kt = 0; kt < 64; ++kt) {
      const int k0 = kt * 64;
      f32x8 av0 = *(const f32x8*)(arow + k0);        // k = k0 + quad*8
      f32x8 av1 = *(const f32x8*)(arow + k0 + 32);   // k = k0+32 + quad*8
      bf16x8 b00 = *(const bf16x8*)(brow0 + k0);
      bf16x8 b01 = *(const bf16x8*)(brow0 + k0 + 32);
      bf16x8 b10 = *(const bf16x8*)(brow1 + k0);
      bf16x8 b11 = *(const bf16x8*)(brow1 + k0 + 32);
      bf16x8 a0 = cvt8(av0);
      bf16x8 a1 = cvt8(av1);
      acc0 = mfma16(a0, b00, acc0);
      acc0 = mfma16(a1, b01, acc0);
      acc1 = mfma16(a0, b10, acc1);
      acc1 = mfma16(a1, b11, acc1);
    }
  }
#pragma unroll
  for (int nbl = 0; nbl < 2; ++nbl) {
    const f32x4 A = nbl ? acc1 : acc0;
    const int col = (nbA + nbl) * 16 + l15;
    const float bav = ba[col];
    const int kb = col >> 3;
#pragma unroll
    for (int i = 0; i < 4; ++i) {
      const int r = quad * 4 + i;                    // C/D: col=lane&15, row=quad*4+reg
      sX[(r * 16 + (kb ^ r)) * 8 + (col & 7)] = f2bf(fast_tanh(A[i] + bav));
    }
  }
  __syncthreads();   // sX complete (all 8 N-blocks)

  // ---- Phase B: GRU layer 0, wave computes gate cols [32w, 32w+32) ----
  bf16x8 ax[4], ah[4];
  {
    const float* hrow = h0 + (size_t)(row0 + l15) * H + quad * 8;
#pragma unroll
    for (int ks = 0; ks < 4; ++ks) {
      const int kb = ks * 4 + quad;
      ax[ks] = *(const bf16x8*)&sX[(l15 * 16 + (kb ^ l15)) * 8];
      ah[ks] = cvt8(*(const f32x8*)(hrow + ks * 32));
    }
  }
#pragma unroll
  for (int nbl = 0; nbl < 2; ++nbl) {
    const int nrow = (nbA + nbl) * 16 + l15;
    f32x4 air = {}, ahr = {}, aiz = {}, ahz = {}, ain = {}, ahn = {};
#pragma unroll
    for (int ks = 0; ks < 4; ++ks) {
      const int k = ks * 32 + quad * 8;
      bf16x8 b;
      b = *(const bf16x8*)(Wih0T + (size_t)(nrow      ) * H + k); air = mfma16(ax[ks], b, air);
      b = *(const bf16x8*)(Wih0T + (size_t)(nrow + 128) * H + k); aiz = mfma16(ax[ks], b, aiz);
      b = *(const bf16x8*)(Wih0T + (size_t)(nrow + 256) * H + k); ain = mfma16(ax[ks], b, ain);
      b = *(const bf16x8*)(Whh0T + (size_t)(nrow      ) * H + k); ahr = mfma16(ah[ks], b, ahr);
      b = *(const bf16x8*)(Whh0T + (size_t)(nrow + 128) * H + k); ahz = mfma16(ah[ks], b, ahz);
      b = *(const bf16x8*)(Whh0T + (size_t)(nrow + 256) * H + k); ahn = mfma16(ah[ks], b, ahn);
    }
    const int col = nrow;
    const float b_ir = bih0[col],       b_hr = bhh0[col];
    const float b_iz = bih0[col + 128], b_hz = bhh0[col + 128];
    const float b_in = bih0[col + 256], b_hn = bhh0[col + 256];
    const int kb = col >> 3;
#pragma unroll
    for (int i = 0; i < 4; ++i) {
      const int r = quad * 4 + i;
      const int grow = row0 + r;
      const float rr = sigm(air[i] + ahr[i] + b_ir + b_hr);
      const float zz = sigm(aiz[i] + ahz[i] + b_iz + b_hz);
      const float nn = fast_tanh(ain[i] + b_in + rr * (ahn[i] + b_hn));
      const float hv = h0[(size_t)grow * H + col];            // fp32, exact
      const float hnew = (1.0f - zz) * nn + zz * hv;
      out[OUT_H0N + (size_t)grow * H + col] = hnew;
      sC[(r * 16 + (kb ^ r)) * 8 + (col & 7)] = f2bf(0.5f * hnew + 0.25f);  // hc0
    }
  }
  __syncthreads();   // sC (hc0) complete

  // ---- Heads 0: v0 + term, wave computes cols [16w, 16w+16) ----
  {
    int ch[4];
#pragma unroll
    for (int i = 0; i < 4; ++i) ch[i] = chosen[row0 + quad * 4 + i];
    bf16x8 ac[4];
#pragma unroll
    for (int ks = 0; ks < 4; ++ks) {
      const int kb = ks * 4 + quad;
      ac[ks] = *(const bf16x8*)&sC[(l15 * 16 + (kb ^ l15)) * 8];
    }
    f32x4 av = {}, at = {};
    const int nrow = w * 16 + l15;
#pragma unroll
    for (int ks = 0; ks < 4; ++ks) {
      const int k = ks * 32 + quad * 8;
      bf16x8 b;
      b = *(const bf16x8*)(Wv0T + (size_t)nrow * H + k); av = mfma16(ac[ks], b, av);
      b = *(const bf16x8*)(Wt0T + (size_t)nrow * H + k); at = mfma16(ac[ks], b, at);
    }
    const int col = nrow;
    const float bvv = bv0[col], btv = bt0[col];
#pragma unroll
    for (int i = 0; i < 4; ++i) {
      const int grow = row0 + quad * 4 + i;
      out[OUT_V0 + (size_t)grow * NOPT + col] = av[i] + bvv;
      if (ch[i] == col)
        out[OUT_TERMP + grow] = sigm(at[i] + btv);
    }
  }
  __syncthreads();   // head-0 reads of sC done; safe to overwrite with hc1

  // ---- Phase C: GRU layer 1 (x1 = [attn | h1]), wave computes cols [32w, 32w+32) ----
  bf16x8 ah1[4];
  {
    const float* hrow = h1 + (size_t)(row0 + l15) * H + quad * 8;
#pragma unroll
    for (int ks = 0; ks < 4; ++ks)
      ah1[ks] = cvt8(*(const f32x8*)(hrow + ks * 32));
  }
#pragma unroll
  for (int nbl = 0; nbl < 2; ++nbl) {
    const int nrow = (nbA + nbl) * 16 + l15;
    f32x4 air = {}, ahr = {}, aiz = {}, ahz = {}, ain = {}, ahn = {};
#pragma unroll
    for (int ks = 0; ks < 8; ++ks) {   // gi1 over K=256: x1 = [attn | h1]
      const int k = ks * 32 + quad * 8;
      const bf16x8 a = (ks < 4) ? ax[ks] : ah1[ks - 4];
      bf16x8 b;
      b = *(const bf16x8*)(Wih1T + (size_t)(nrow      ) * 256 + k); air = mfma16(a, b, air);
      b = *(const bf16x8*)(Wih1T + (size_t)(nrow + 128) * 256 + k); aiz = mfma16(a, b, aiz);
      b = *(const bf16x8*)(Wih1T + (size_t)(nrow + 256) * 256 + k); ain = mfma16(a, b, ain);
    }
#pragma unroll
    for (int ks = 0; ks < 4; ++ks) {   // gh1 over K=128
      const int k = ks * 32 + quad * 8;
      bf16x8 b;
      b = *(const bf16x8*)(Whh1T + (size_t)(nrow      ) * H + k); ahr = mfma16(ah1[ks], b, ahr);
      b = *(const bf16x8*)(Whh1T + (size_t)(nrow + 128) * H + k); ahz = mfma16(ah1[ks], b, ahz);
      b = *(const bf16x8*)(Whh1T + (size_t)(nrow + 256) * H + k); ahn = mfma16(ah1[ks], b, ahn);
    }
    const int col = nrow;
    const float b_ir = bih1[col],       b_hr = bhh1[col];
    const float b_iz = bih1[col + 128], b_hz = bhh1[col + 128];
    const float b_in = bih1[col + 256], b_hn = bhh1[col + 256];
    const int kb = col >> 3;
#pragma unroll
    for (int i = 0; i < 4; ++i) {
      const int r = quad * 4 + i;
      const int grow = row0 + r;
      const float rr = sigm(air[i] + ahr[i] + b_ir + b_hr);
      const float zz = sigm(aiz[i] + ahz[i] + b_iz + b_hz);
      const float nn = fast_tanh(ain[i] + b_in + rr * (ahn[i] + b_hn));
      const float hv = h1[(size_t)grow * H + col];
      const float hnew = (1.0f - zz) * nn + zz * hv;
      out[OUT_H1N + (size_t)grow * H + col] = hnew;
      sC[(r * 16 + (kb ^ r)) * 8 + (col & 7)] = f2bf(0.5f * hnew + 0.25f);  // hc1
    }
  }
  __syncthreads();   // sC (hc1) complete

  // ---- Head 1: v1, wave computes cols [16w, 16w+16) ----
  {
    bf16x8 ac[4];
#pragma unroll
    for (int ks = 0; ks < 4; ++ks) {
      const int kb = ks * 4 + quad;
      ac[ks] = *(const bf16x8*)&sC[(l15 * 16 + (kb ^ l15)) * 8];
    }
    f32x4 av = {};
    const int nrow = w * 16 + l15;
#pragma unroll
    for (int ks = 0; ks < 4; ++ks) {
      const int k = ks * 32 + quad * 8;
      bf16x8 b = *(const bf16x8*)(Wv1T + (size_t)nrow * H + k);
      av = mfma16(ac[ks], b, av);
    }
    const int col = nrow;
    const float bvv = bv1[col];
#pragma unroll
    for (int i = 0; i < 4; ++i) {
      const int grow = row0 + quad * 4 + i;
      out[OUT_V1 + (size_t)grow * NOPT + col] = av[i] + bvv;
    }
  }
}

extern "C" void kernel_launch(void* const* d_in, const int* in_sizes, int n_in,
                              void* d_out, int out_size, void* d_ws, size_t ws_size,
                              hipStream_t stream) {
  (void)in_sizes; (void)n_in; (void)out_size; (void)ws_size;
  const float* obs    = (const float*)d_in[0];
  const int*   chosen = (const int*)d_in[1];
  const float* h0     = (const float*)d_in[2];
  const float* h1     = (const float*)d_in[3];
  const float* Wa     = (const float*)d_in[4];
  const float* ba     = (const float*)d_in[5];
  const float* Wih0   = (const float*)d_in[6];
  const float* Whh0   = (const float*)d_in[7];
  const float* bih0   = (const float*)d_in[8];
  const float* bhh0   = (const float*)d_in[9];
  const float* Wih1   = (const float*)d_in[10];
  const float* Whh1   = (const float*)d_in[11];
  const float* bih1   = (const float*)d_in[12];
  const float* bhh1   = (const float*)d_in[13];
  const float* Wv0    = (const float*)d_in[14];
  const float* bv0    = (const float*)d_in[15];
  const float* Wv1    = (const float*)d_in[16];
  const float* bv1    = (const float*)d_in[17];
  const float* Wt0    = (const float*)d_in[18];
  const float* bt0    = (const float*)d_in[19];
  uint16_t* ws  = (uint16_t*)d_ws;
  float*    out = (float*)d_out;

  hipLaunchKernelGGL(k_transpose, dim3(3104), dim3(256), 0, stream,
                     Wa, Wih0, Whh0, Wih1, Whh1, Wv0, Wv1, Wt0, ws);
  hipLaunchKernelGGL(k_fused, dim3(1024), dim3(256), 0, stream,
                     obs, ws, ba, h0, bih0, bhh0, bv0, bt0, chosen,
                     h1, bih1, bhh1, bv1, out);
}

// Round 3
// 521.084 us; speedup vs baseline: 1.1909x; 1.1909x over previous
//
#include <hip/hip_runtime.h>
#include <hip/hip_bf16.h>
#include <stdint.h>

// HierarchicalGRU on MI355X. B=16384, IN=4096, H=128, NOPT=64.
// Round 7: fix HBM-latency bound (in-flight bytes) + k_transpose coalescing.
//  - Phase A: cooperative double-buffered LDS staging of obs (16x128 fp32 tile,
//    8KB issued per block per iter -> ~32KB/CU concurrent HBM demand > 9.2KB
//    Little's-law requirement). Staging regs: one f32x8 per thread.
//  - B-fragments (WaT) prefetched to regs BEFORE the barrier so L2 latency
//    hides under the barrier's vmcnt drain.
//  - k_transpose: 32x32 LDS-tiled, coalesced reads AND writes (was stride-N
//    reads, est. ~140us; now <10us).
//  - Phases B/C/heads unchanged from round 6 (verified numerics).

typedef __attribute__((ext_vector_type(8))) short bf16x8;
typedef __attribute__((ext_vector_type(4))) float f32x4;
typedef __attribute__((ext_vector_type(8))) float f32x8;

#define INDIM 4096
#define H 128
#define NOPT 64

// workspace layout (uint16 element offsets), bf16 contents
#define WS_WAT    0u        // [128, 4096]
#define WS_WIH0T  524288u   // [384, 128]
#define WS_WHH0T  573440u   // [384, 128]
#define WS_WIH1T  622592u   // [384, 256]
#define WS_WHH1T  720896u   // [384, 128]
#define WS_WV0T   770048u   // [64, 128]
#define WS_WV1T   778240u   // [64, 128]
#define WS_WT0T   786432u   // [64, 128]

// output layout (fp32 element offsets): v0[B,64], term_p[B,1], v1[B,64], h0n[B,128], h1n[B,128]
#define OUT_V0    0u
#define OUT_TERMP 1048576u
#define OUT_V1    1064960u
#define OUT_H0N   2113536u
#define OUT_H1N   4210688u

static __device__ __forceinline__ uint16_t f2bf(float f) {
  __hip_bfloat16 h = __float2bfloat16(f);   // RNE; compiler packs pairs into v_cvt_pk_bf16_f32
  return __builtin_bit_cast(uint16_t, h);
}
static __device__ __forceinline__ float sigm(float x) { return 1.0f / (1.0f + __expf(-x)); }
static __device__ __forceinline__ float fast_tanh(float x) {
  float e = __expf(2.0f * x);          // e=inf -> 1, e=0 -> -1: saturates correctly
  return 1.0f - 2.0f / (e + 1.0f);
}
static __device__ __forceinline__ f32x4 mfma16(bf16x8 a, bf16x8 b, f32x4 c) {
  return __builtin_amdgcn_mfma_f32_16x16x32_bf16(a, b, c, 0, 0, 0);
}
static __device__ __forceinline__ bf16x8 cvt8(f32x8 v) {
  bf16x8 r;
#pragma unroll
  for (int j = 0; j < 8; ++j) r[j] = (short)f2bf(v[j]);
  return r;
}

// ---------------- K0: weight transpose+convert  W[K,N] fp32 -> WT[N,K] bf16 ----------------
// 32x32 LDS-tiled: coalesced reads (along N) and coalesced writes (along K).
__global__ void k_transpose(const float* __restrict__ Wa,
                            const float* __restrict__ Wih0,
                            const float* __restrict__ Whh0,
                            const float* __restrict__ Wih1,
                            const float* __restrict__ Whh1,
                            const float* __restrict__ Wv0,
                            const float* __restrict__ Wv1,
                            const float* __restrict__ Wt0,
                            uint16_t* __restrict__ ws) {
  __shared__ float sT[32][34];   // +2 pad: write stride 34 -> bank step 2 (free)
  int blk = blockIdx.x;
  const float* in; uint16_t* out; int K; int N; int base;
  if (blk < 512)      { in = Wa;   out = ws + WS_WAT;   K = 4096; N = 128; base = 0; }
  else if (blk < 560) { in = Wih0; out = ws + WS_WIH0T; K = 128;  N = 384; base = 512; }
  else if (blk < 608) { in = Whh0; out = ws + WS_WHH0T; K = 128;  N = 384; base = 560; }
  else if (blk < 704) { in = Wih1; out = ws + WS_WIH1T; K = 256;  N = 384; base = 608; }
  else if (blk < 752) { in = Whh1; out = ws + WS_WHH1T; K = 128;  N = 384; base = 704; }
  else if (blk < 760) { in = Wv0;  out = ws + WS_WV0T;  K = 128;  N = 64;  base = 752; }
  else if (blk < 768) { in = Wv1;  out = ws + WS_WV1T;  K = 128;  N = 64;  base = 760; }
  else                { in = Wt0;  out = ws + WS_WT0T;  K = 128;  N = 64;  base = 768; }
  const int tix = blk - base;
  const int nTK = K >> 5;                 // K-tile count (power of 2 for all)
  const int kt = tix & (nTK - 1);
  const int nt = tix / nTK;
  const int k0 = kt * 32, n0 = nt * 32;
  const int t = threadIdx.x;
#pragma unroll
  for (int i = 0; i < 4; ++i) {           // read: consecutive t -> consecutive n
    int e = i * 256 + t, kk = e >> 5, nn = e & 31;
    sT[kk][nn] = in[(size_t)(k0 + kk) * N + n0 + nn];
  }
  __syncthreads();
#pragma unroll
  for (int i = 0; i < 4; ++i) {           // write: consecutive t -> consecutive k
    int e = i * 256 + t, nn = e >> 5, kk = e & 31;
    out[(size_t)(n0 + nn) * K + k0 + kk] = f2bf(sT[kk][nn]);
  }
}

// ---------------- K1: fused attn -> gru0(+v0/term) -> gru1(+v1) ----------------
// 1024 blocks x 256 thr (4 waves). Block owns 16 rows; wave w owns N-blocks
// {2w, 2w+1} of the 128-wide GEMMs and col-block w of the 64-wide heads.
__launch_bounds__(256, 4)
__global__ void k_fused(const float* __restrict__ obs,
                        const uint16_t* __restrict__ ws,
                        const float* __restrict__ ba,
                        const float* __restrict__ h0,
                        const float* __restrict__ bih0,
                        const float* __restrict__ bhh0,
                        const float* __restrict__ bv0,
                        const float* __restrict__ bt0,
                        const int* __restrict__ chosen,
                        const float* __restrict__ h1,
                        const float* __restrict__ bih1,
                        const float* __restrict__ bhh1,
                        const float* __restrict__ bv1,
                        float* __restrict__ out) {
  // obs staging: 16 rows x 128 k (bf16), XOR-swizzled slots, double-buffered.
  __shared__ uint16_t sObs[2][16 * 16 * 8];
  __shared__ uint16_t sX[16 * 16 * 8];   // attn tile (A-frag layout)
  __shared__ uint16_t sC[16 * 16 * 8];   // hc tile (hc0 then hc1)
  const uint16_t* WaT   = ws + WS_WAT;
  const uint16_t* Wih0T = ws + WS_WIH0T;
  const uint16_t* Whh0T = ws + WS_WHH0T;
  const uint16_t* Wih1T = ws + WS_WIH1T;
  const uint16_t* Whh1T = ws + WS_WHH1T;
  const uint16_t* Wv0T  = ws + WS_WV0T;
  const uint16_t* Wv1T  = ws + WS_WV1T;
  const uint16_t* Wt0T  = ws + WS_WT0T;
  const int t = threadIdx.x, w = t >> 6, lane = t & 63;
  const int l15 = lane & 15, quad = lane >> 4;
  const int row0 = blockIdx.x * 16;        // block's 16 rows
  const int nbA = 2 * w;                   // wave's first N-block (of 8)

  // ---- Phase A: attn = tanh(obs @ WaT^T + ba), wave computes cols [32w, 32w+32) ----
  f32x4 acc0 = {}, acc1 = {};
  {
    const int r16 = t >> 4;                // staging row 0..15
    const int kb16 = t & 15;               // staging 8-elem k-block within BK=128
    const float* aptr = obs + (size_t)(row0 + r16) * INDIM + kb16 * 8;
    const int wslot = (r16 * 16 + (kb16 ^ r16)) * 8;
    const uint16_t* brow0 = WaT + (size_t)(nbA * 16 + l15) * INDIM + quad * 8;
    const uint16_t* brow1 = brow0 + (size_t)16 * INDIM;
    f32x8 stg = *(const f32x8*)(aptr);     // tile 0
    for (int kt = 0; kt < 32; ++kt) {
      // commit current tile to LDS (bf16, swizzled)
      *(bf16x8*)&sObs[kt & 1][wslot] = cvt8(stg);
      // issue next obs tile (flies across the barrier drain window)
      if (kt < 31) stg = *(const f32x8*)(aptr + (size_t)(kt + 1) * 128);
      // prefetch this tile's B-fragments (L2-hot WaT) before the barrier
      bf16x8 b[8];
      const int kO = kt * 128;
#pragma unroll
      for (int s = 0; s < 4; ++s) {
        b[s]     = *(const bf16x8*)(brow0 + kO + s * 32);
        b[4 + s] = *(const bf16x8*)(brow1 + kO + s * 32);
      }
      __syncthreads();                     // staged tile visible (drains loads)
#pragma unroll
      for (int s = 0; s < 4; ++s) {
        bf16x8 afr = *(const bf16x8*)&sObs[kt & 1][(l15 * 16 + ((s * 4 + quad) ^ l15)) * 8];
        acc0 = mfma16(afr, b[s], acc0);
        acc1 = mfma16(afr, b[4 + s], acc1);
      }
    }
  }
#pragma unroll
  for (int nbl = 0; nbl < 2; ++nbl) {
    const f32x4 A = nbl ? acc1 : acc0;
    const int col = (nbA + nbl) * 16 + l15;
    const float bav = ba[col];
    const int kb = col >> 3;
#pragma unroll
    for (int i = 0; i < 4; ++i) {
      const int r = quad * 4 + i;                    // C/D: col=lane&15, row=quad*4+reg
      sX[(r * 16 + (kb ^ r)) * 8 + (col & 7)] = f2bf(fast_tanh(A[i] + bav));
    }
  }
  __syncthreads();   // sX complete (all 8 N-blocks)

  // ---- Phase B: GRU layer 0, wave computes gate cols [32w, 32w+32) ----
  bf16x8 ax[4], ah[4];
  {
    const float* hrow = h0 + (size_t)(row0 + l15) * H + quad * 8;
#pragma unroll
    for (int ks = 0; ks < 4; ++ks) {
      const int kb = ks * 4 + quad;
      ax[ks] = *(const bf16x8*)&sX[(l15 * 16 + (kb ^ l15)) * 8];
      ah[ks] = cvt8(*(const f32x8*)(hrow + ks * 32));
    }
  }
#pragma unroll
  for (int nbl = 0; nbl < 2; ++nbl) {
    const int nrow = (nbA + nbl) * 16 + l15;
    f32x4 air = {}, ahr = {}, aiz = {}, ahz = {}, ain = {}, ahn = {};
#pragma unroll
    for (int ks = 0; ks < 4; ++ks) {
      const int k = ks * 32 + quad * 8;
      bf16x8 b;
      b = *(const bf16x8*)(Wih0T + (size_t)(nrow      ) * H + k); air = mfma16(ax[ks], b, air);
      b = *(const bf16x8*)(Wih0T + (size_t)(nrow + 128) * H + k); aiz = mfma16(ax[ks], b, aiz);
      b = *(const bf16x8*)(Wih0T + (size_t)(nrow + 256) * H + k); ain = mfma16(ax[ks], b, ain);
      b = *(const bf16x8*)(Whh0T + (size_t)(nrow      ) * H + k); ahr = mfma16(ah[ks], b, ahr);
      b = *(const bf16x8*)(Whh0T + (size_t)(nrow + 128) * H + k); ahz = mfma16(ah[ks], b, ahz);
      b = *(const bf16x8*)(Whh0T + (size_t)(nrow + 256) * H + k); ahn = mfma16(ah[ks], b, ahn);
    }
    const int col = nrow;
    const float b_ir = bih0[col],       b_hr = bhh0[col];
    const float b_iz = bih0[col + 128], b_hz = bhh0[col + 128];
    const float b_in = bih0[col + 256], b_hn = bhh0[col + 256];
    const int kb = col >> 3;
#pragma unroll
    for (int i = 0; i < 4; ++i) {
      const int r = quad * 4 + i;
      const int grow = row0 + r;
      const float rr = sigm(air[i] + ahr[i] + b_ir + b_hr);
      const float zz = sigm(aiz[i] + ahz[i] + b_iz + b_hz);
      const float nn = fast_tanh(ain[i] + b_in + rr * (ahn[i] + b_hn));
      const float hv = h0[(size_t)grow * H + col];            // fp32, exact
      const float hnew = (1.0f - zz) * nn + zz * hv;
      out[OUT_H0N + (size_t)grow * H + col] = hnew;
      sC[(r * 16 + (kb ^ r)) * 8 + (col & 7)] = f2bf(0.5f * hnew + 0.25f);  // hc0
    }
  }
  __syncthreads();   // sC (hc0) complete

  // ---- Heads 0: v0 + term, wave computes cols [16w, 16w+16) ----
  {
    int ch[4];
#pragma unroll
    for (int i = 0; i < 4; ++i) ch[i] = chosen[row0 + quad * 4 + i];
    bf16x8 ac[4];
#pragma unroll
    for (int ks = 0; ks < 4; ++ks) {
      const int kb = ks * 4 + quad;
      ac[ks] = *(const bf16x8*)&sC[(l15 * 16 + (kb ^ l15)) * 8];
    }
    f32x4 av = {}, at = {};
    const int nrow = w * 16 + l15;
#pragma unroll
    for (int ks = 0; ks < 4; ++ks) {
      const int k = ks * 32 + quad * 8;
      bf16x8 b;
      b = *(const bf16x8*)(Wv0T + (size_t)nrow * H + k); av = mfma16(ac[ks], b, av);
      b = *(const bf16x8*)(Wt0T + (size_t)nrow * H + k); at = mfma16(ac[ks], b, at);
    }
    const int col = nrow;
    const float bvv = bv0[col], btv = bt0[col];
#pragma unroll
    for (int i = 0; i < 4; ++i) {
      const int grow = row0 + quad * 4 + i;
      out[OUT_V0 + (size_t)grow * NOPT + col] = av[i] + bvv;
      if (ch[i] == col)
        out[OUT_TERMP + grow] = sigm(at[i] + btv);
    }
  }
  __syncthreads();   // head-0 reads of sC done; safe to overwrite with hc1

  // ---- Phase C: GRU layer 1 (x1 = [attn | h1]), wave computes cols [32w, 32w+32) ----
  bf16x8 ah1[4];
  {
    const float* hrow = h1 + (size_t)(row0 + l15) * H + quad * 8;
#pragma unroll
    for (int ks = 0; ks < 4; ++ks)
      ah1[ks] = cvt8(*(const f32x8*)(hrow + ks * 32));
  }
#pragma unroll
  for (int nbl = 0; nbl < 2; ++nbl) {
    const int nrow = (nbA + nbl) * 16 + l15;
    f32x4 air = {}, ahr = {}, aiz = {}, ahz = {}, ain = {}, ahn = {};
#pragma unroll
    for (int ks = 0; ks < 8; ++ks) {   // gi1 over K=256: x1 = [attn | h1]
      const int k = ks * 32 + quad * 8;
      const bf16x8 a = (ks < 4) ? ax[ks] : ah1[ks - 4];
      bf16x8 b;
      b = *(const bf16x8*)(Wih1T + (size_t)(nrow      ) * 256 + k); air = mfma16(a, b, air);
      b = *(const bf16x8*)(Wih1T + (size_t)(nrow + 128) * 256 + k); aiz = mfma16(a, b, aiz);
      b = *(const bf16x8*)(Wih1T + (size_t)(nrow + 256) * 256 + k); ain = mfma16(a, b, ain);
    }
#pragma unroll
    for (int ks = 0; ks < 4; ++ks) {   // gh1 over K=128
      const int k = ks * 32 + quad * 8;
      bf16x8 b;
      b = *(const bf16x8*)(Whh1T + (size_t)(nrow      ) * H + k); ahr = mfma16(ah1[ks], b, ahr);
      b = *(const bf16x8*)(Whh1T + (size_t)(nrow + 128) * H + k); ahz = mfma16(ah1[ks], b, ahz);
      b = *(const bf16x8*)(Whh1T + (size_t)(nrow + 256) * H + k); ahn = mfma16(ah1[ks], b, ahn);
    }
    const int col = nrow;
    const float b_ir = bih1[col],       b_hr = bhh1[col];
    const float b_iz = bih1[col + 128], b_hz = bhh1[col + 128];
    const float b_in = bih1[col + 256], b_hn = bhh1[col + 256];
    const int kb = col >> 3;
#pragma unroll
    for (int i = 0; i < 4; ++i) {
      const int r = quad * 4 + i;
      const int grow = row0 + r;
      const float rr = sigm(air[i] + ahr[i] + b_ir + b_hr);
      const float zz = sigm(aiz[i] + ahz[i] + b_iz + b_hz);
      const float nn = fast_tanh(ain[i] + b_in + rr * (ahn[i] + b_hn));
      const float hv = h1[(size_t)grow * H + col];
      const float hnew = (1.0f - zz) * nn + zz * hv;
      out[OUT_H1N + (size_t)grow * H + col] = hnew;
      sC[(r * 16 + (kb ^ r)) * 8 + (col & 7)] = f2bf(0.5f * hnew + 0.25f);  // hc1
    }
  }
  __syncthreads();   // sC (hc1) complete

  // ---- Head 1: v1, wave computes cols [16w, 16w+16) ----
  {
    bf16x8 ac[4];
#pragma unroll
    for (int ks = 0; ks < 4; ++ks) {
      const int kb = ks * 4 + quad;
      ac[ks] = *(const bf16x8*)&sC[(l15 * 16 + (kb ^ l15)) * 8];
    }
    f32x4 av = {};
    const int nrow = w * 16 + l15;
#pragma unroll
    for (int ks = 0; ks < 4; ++ks) {
      const int k = ks * 32 + quad * 8;
      bf16x8 b = *(const bf16x8*)(Wv1T + (size_t)nrow * H + k);
      av = mfma16(ac[ks], b, av);
    }
    const int col = nrow;
    const float bvv = bv1[col];
#pragma unroll
    for (int i = 0; i < 4; ++i) {
      const int grow = row0 + quad * 4 + i;
      out[OUT_V1 + (size_t)grow * NOPT + col] = av[i] + bvv;
    }
  }
}

extern "C" void kernel_launch(void* const* d_in, const int* in_sizes, int n_in,
                              void* d_out, int out_size, void* d_ws, size_t ws_size,
                              hipStream_t stream) {
  (void)in_sizes; (void)n_in; (void)out_size; (void)ws_size;
  const float* obs    = (const float*)d_in[0];
  const int*   chosen = (const int*)d_in[1];
  const float* h0     = (const float*)d_in[2];
  const float* h1     = (const float*)d_in[3];
  const float* Wa     = (const float*)d_in[4];
  const float* ba     = (const float*)d_in[5];
  const float* Wih0   = (const float*)d_in[6];
  const float* Whh0   = (const float*)d_in[7];
  const float* bih0   = (const float*)d_in[8];
  const float* bhh0   = (const float*)d_in[9];
  const float* Wih1   = (const float*)d_in[10];
  const float* Whh1   = (const float*)d_in[11];
  const float* bih1   = (const float*)d_in[12];
  const float* bhh1   = (const float*)d_in[13];
  const float* Wv0    = (const float*)d_in[14];
  const float* bv0    = (const float*)d_in[15];
  const float* Wv1    = (const float*)d_in[16];
  const float* bv1    = (const float*)d_in[17];
  const float* Wt0    = (const float*)d_in[18];
  const float* bt0    = (const float*)d_in[19];
  uint16_t* ws  = (uint16_t*)d_ws;
  float*    out = (float*)d_out;

  hipLaunchKernelGGL(k_transpose, dim3(776), dim3(256), 0, stream,
                     Wa, Wih0, Whh0, Wih1, Whh1, Wv0, Wv1, Wt0, ws);
  hipLaunchKernelGGL(k_fused, dim3(1024), dim3(256), 0, stream,
                     obs, ws, ba, h0, bih0, bhh0, bv0, bt0, chosen,
                     h1, bih1, bhh1, bv1, out);
}